// Round 4
// baseline (168.939 us; speedup 1.0000x reference)
//
#include <hip/hip_runtime.h>
#include <math.h>

#define Bb   4
#define Nn   2048
#define Dd   256
#define Hh   4
#define HDd  64
#define BN   (Bb * Nn)

typedef float v4f __attribute__((ext_vector_type(4)));
typedef short v8s __attribute__((ext_vector_type(8)));

__device__ __forceinline__ unsigned rne_bf16(float f) {
    unsigned u = __float_as_uint(f);
    u += 0x7fffu + ((u >> 16) & 1u);
    return u >> 16;
}

// ---------------------------------------------------------------------------
// Kernel 1: role-split grid of 1024 blocks.
//   bid even -> gemm block g=bid>>1 (lands on EVEN XCDs: 512 blocks on 128
//              CUs = 4/CU fully resident, 2x the waves/SIMD of v4), swizzled
//              so one m-tile's 4 heads share an XCD (x-tile L2-shared).
//   bid odd  -> adj->bitmask compress c=bid>>1 (ODD XCDs, all resident at
//              t=0 -> the 67MB stream overlaps gemm instead of tailing it).
// Gemm math/epilogue unchanged from v1-v4.
// ---------------------------------------------------------------------------
__global__ __launch_bounds__(256, 2) void k_gemm(const float* __restrict__ x,
                                                 const float* __restrict__ W,
                                                 const float* __restrict__ a_src,
                                                 const float* __restrict__ a_dst,
                                                 const float* __restrict__ adj,
                                                 unsigned short* __restrict__ hbf,
                                                 float* __restrict__ ssrc,
                                                 float* __restrict__ sdst,
                                                 unsigned long long* __restrict__ bitadj) {
    __shared__ __align__(16) unsigned short xs[2][64 * 72];  // hi, lo  (T reuses xs)
    __shared__ __align__(16) unsigned short wsm[2][64 * 72];
    __shared__ float asd[128];

    const int bid0 = (int)blockIdx.x;
    if (bid0 & 1) {
        // ---- adj f32 -> bitmask. word w covers row (w>>5), j in [(w&31)*64,+64)
        // 262144 words; 2048 compress waves x 32 iters x 4 words.
        const int gw = (bid0 >> 1) * 4 + ((int)threadIdx.x >> 6);
        const int lane = (int)threadIdx.x & 63;
#pragma unroll 1
        for (int w = gw * 4; w < 262144; w += 2048 * 4) {
            float v0 = adj[(size_t)((w + 0) >> 5) * 2048 + ((w + 0) & 31) * 64 + lane];
            float v1 = adj[(size_t)((w + 1) >> 5) * 2048 + ((w + 1) & 31) * 64 + lane];
            float v2 = adj[(size_t)((w + 2) >> 5) * 2048 + ((w + 2) & 31) * 64 + lane];
            float v3 = adj[(size_t)((w + 3) >> 5) * 2048 + ((w + 3) & 31) * 64 + lane];
            unsigned long long m0 = __ballot(v0 != 0.0f);
            unsigned long long m1 = __ballot(v1 != 0.0f);
            unsigned long long m2 = __ballot(v2 != 0.0f);
            unsigned long long m3 = __ballot(v3 != 0.0f);
            if (lane == 0) {
                bitadj[w + 0] = m0;
                bitadj[w + 1] = m1;
                bitadj[w + 2] = m2;
                bitadj[w + 3] = m3;
            }
        }
        return;
    }

    const int g = bid0 >> 1;                       // [0,512)
    const int head = (g >> 2) & 3;                 // XCD = (2g)&7 = 2*(g&3):
    const int mtile = (g & 3) + 4 * (g >> 4);      // heads of one m-tile share XCD
    const int tid = threadIdx.x;
    const int m0 = mtile * 64;
    const int n0 = head * 64;
    const int b = m0 >> 11;
    const int i0loc = m0 & 2047;

    if (tid < 128) {
        int sel = tid >> 6, d = tid & 63;
        asd[tid] = sel ? a_dst[n0 + d] : a_src[n0 + d];
    }

    const int wv = tid >> 6, ln = tid & 63, l15 = ln & 15, l4 = ln >> 4;
    const int mh = wv >> 1, nh = wv & 1;
    const int srow = tid >> 2, kq = (tid & 3) * 16;

    v4f acc[2][2];
#pragma unroll
    for (int gg = 0; gg < 2; ++gg)
#pragma unroll
        for (int t = 0; t < 2; ++t) acc[gg][t] = (v4f){0.f, 0.f, 0.f, 0.f};

    for (int st = 0; st < 4; ++st) {
        const int k0 = st * 64;
        __syncthreads();
        // ---- stage x and W tiles as bf16 hi/lo ----
        {
            float xf[16], wf[16];
            const float* xp = x + (size_t)(m0 + srow) * Dd + k0 + kq;
            const float* wp = W + (size_t)(n0 + srow) * Dd + k0 + kq;
#pragma unroll
            for (int q = 0; q < 4; ++q) {
                *(float4*)&xf[q * 4] = *(const float4*)(xp + q * 4);
                *(float4*)&wf[q * 4] = *(const float4*)(wp + q * 4);
            }
            unsigned xh[8], xl[8], wh[8], wl[8];
#pragma unroll
            for (int j = 0; j < 8; ++j) {
                unsigned h0 = rne_bf16(xf[2 * j]), h1 = rne_bf16(xf[2 * j + 1]);
                float l0 = xf[2 * j] - __uint_as_float(h0 << 16);
                float l1 = xf[2 * j + 1] - __uint_as_float(h1 << 16);
                xh[j] = h0 | (h1 << 16);
                xl[j] = rne_bf16(l0) | (rne_bf16(l1) << 16);
                unsigned g0 = rne_bf16(wf[2 * j]), g1 = rne_bf16(wf[2 * j + 1]);
                float m0f = wf[2 * j] - __uint_as_float(g0 << 16);
                float m1f = wf[2 * j + 1] - __uint_as_float(g1 << 16);
                wh[j] = g0 | (g1 << 16);
                wl[j] = rne_bf16(m0f) | (rne_bf16(m1f) << 16);
            }
            *(uint4*)(xs[0] + srow * 72 + kq)     = make_uint4(xh[0], xh[1], xh[2], xh[3]);
            *(uint4*)(xs[0] + srow * 72 + kq + 8) = make_uint4(xh[4], xh[5], xh[6], xh[7]);
            *(uint4*)(xs[1] + srow * 72 + kq)     = make_uint4(xl[0], xl[1], xl[2], xl[3]);
            *(uint4*)(xs[1] + srow * 72 + kq + 8) = make_uint4(xl[4], xl[5], xl[6], xl[7]);
            *(uint4*)(wsm[0] + srow * 72 + kq)     = make_uint4(wh[0], wh[1], wh[2], wh[3]);
            *(uint4*)(wsm[0] + srow * 72 + kq + 8) = make_uint4(wh[4], wh[5], wh[6], wh[7]);
            *(uint4*)(wsm[1] + srow * 72 + kq)     = make_uint4(wl[0], wl[1], wl[2], wl[3]);
            *(uint4*)(wsm[1] + srow * 72 + kq + 8) = make_uint4(wl[4], wl[5], wl[6], wl[7]);
        }
        __syncthreads();
        // ---- MFMA: wave (mh, nh) owns 2x2 16-tiles ----
        {
            v8s ah[2][2], al[2][2], bh_[2][2], bl_[2][2];
#pragma unroll
            for (int gg = 0; gg < 2; ++gg)
#pragma unroll
                for (int kh = 0; kh < 2; ++kh) {
                    int ro = (mh * 32 + gg * 16 + l15) * 72 + kh * 32 + l4 * 8;
                    ah[gg][kh] = *(const v8s*)(xs[0] + ro);
                    al[gg][kh] = *(const v8s*)(xs[1] + ro);
                }
#pragma unroll
            for (int t = 0; t < 2; ++t)
#pragma unroll
                for (int kh = 0; kh < 2; ++kh) {
                    int ro = (nh * 32 + t * 16 + l15) * 72 + kh * 32 + l4 * 8;
                    bh_[t][kh] = *(const v8s*)(wsm[0] + ro);
                    bl_[t][kh] = *(const v8s*)(wsm[1] + ro);
                }
#pragma unroll
            for (int gg = 0; gg < 2; ++gg)
#pragma unroll
                for (int t = 0; t < 2; ++t)
#pragma unroll
                    for (int kh = 0; kh < 2; ++kh) {
                        acc[gg][t] = __builtin_amdgcn_mfma_f32_16x16x32_bf16(ah[gg][kh], bh_[t][kh], acc[gg][t], 0, 0, 0);
                        acc[gg][t] = __builtin_amdgcn_mfma_f32_16x16x32_bf16(al[gg][kh], bh_[t][kh], acc[gg][t], 0, 0, 0);
                        acc[gg][t] = __builtin_amdgcn_mfma_f32_16x16x32_bf16(ah[gg][kh], bl_[t][kh], acc[gg][t], 0, 0, 0);
                    }
        }
    }

    // ---- epilogue: C -> T[d][m] (stride 67) ----
    __syncthreads();
    float* T = (float*)&xs[0][0];   // 64*67*4 = 17168 B
#pragma unroll
    for (int gg = 0; gg < 2; ++gg)
#pragma unroll
        for (int t = 0; t < 2; ++t)
#pragma unroll
            for (int r = 0; r < 4; ++r) {
                int d = nh * 32 + t * 16 + l15;
                int m = mh * 32 + gg * 16 + l4 * 4 + r;
                T[d * 67 + m] = acc[gg][t][r];
            }
    __syncthreads();
    if (tid < 128) {
        // scores -> TRANSPOSED [h][bn]
        int m = tid & 63, sel = tid >> 6;
        float s = 0.f;
#pragma unroll
        for (int d = 0; d < 64; ++d) s += T[d * 67 + m] * asd[sel * 64 + d];
        (sel ? sdst : ssrc)[(size_t)head * BN + (size_t)b * Nn + i0loc + m] = s;
        // hbf pack
        int dloc = tid >> 1, jhh = tid & 1;
        const float* row = T + dloc * 67 + jhh * 32;
        unsigned pk[16];
#pragma unroll
        for (int jj = 0; jj < 16; ++jj)
            pk[jj] = rne_bf16(row[jj * 2]) | (rne_bf16(row[jj * 2 + 1]) << 16);
        unsigned short* dst = hbf +
            ((size_t)((b * 64 + (i0loc >> 5) + jhh) * 256 + head * HDd + dloc)) * 32;
        uint4* d4 = (uint4*)dst;
        d4[0] = make_uint4(pk[0], pk[1], pk[2], pk[3]);
        d4[1] = make_uint4(pk[4], pk[5], pk[6], pk[7]);
        d4[2] = make_uint4(pk[8], pk[9], pk[10], pk[11]);
        d4[3] = make_uint4(pk[12], pk[13], pk[14], pk[15]);
    }
}

// ---------------------------------------------------------------------------
// Kernel 2 (v5): v4 structure + three fixes.
// (1) XCD-bijective block map: xcd=bid&7 -> b=xcd>>1 -> per-XCD working set
//     (1MB hbf plane + 256KB bitadj + sdst) fits the 4MB XCD L2; v4 spread
//     all 4 b-planes over every XCD (6MB in 4MB -> HBM-latency bb loads).
// (2) exp() hoisted OUT of the inner loop: exp(max(s,.2s)) =
//     max(exp(ss)exp(sd), exp(.2ss)exp(.2sd)) (monotonic exp). Per-block
//     LDS d-table (exp(sd),exp(.2sd)) built once; per-lane c1,c2. Inner gen
//     per element = 2 mul + max + cndmask + half a v_cvt_pk_bf16_f32 (RNE).
// (3) bb truly double-buffered one full step ahead (~120 VGPR < 128 cap).
// red aliases the dead dtab after the loop (extra sync guards the overlap).
// ---------------------------------------------------------------------------
__global__ __launch_bounds__(512, 4) void k_aggr(const unsigned short* __restrict__ hbf,
                                                 const unsigned long long* __restrict__ bitadj,
                                                 const float* __restrict__ ssrc,
                                                 const float* __restrict__ sdst,
                                                 float* __restrict__ out) {
    __shared__ __align__(16) float dtab[4 * 2048 * 2];   // 64 KB; aliased as red later

    const int tid = threadIdx.x;
    const int bid = (int)blockIdx.x;
    const int xcd = bid & 7;
    const int b   = xcd >> 1;                         // one b per XCD pair
    const int i0  = (((bid >> 3) << 1) | (xcd & 1)) * 16;

    const int wv = tid >> 6;
    const int h  = wv & 3;                 // wave's head
    const int jh = wv >> 2;                // wave's j-half (16 steps of 64 j)
    const int ln = tid & 63, l15 = ln & 15, l4 = ln >> 4;

    // ---- build d-table once: (h,j) -> (exp(sd), exp(0.2 sd)) ----
    for (int q = tid; q < 2048; q += 512) {
        int hh = q >> 9, j4 = (q & 511) * 4;
        float4 sv = *(const float4*)(sdst + (size_t)hh * BN + (size_t)b * Nn + j4);
        float4 o0 = make_float4(__expf(sv.x), __expf(0.2f * sv.x),
                                __expf(sv.y), __expf(0.2f * sv.y));
        float4 o1 = make_float4(__expf(sv.z), __expf(0.2f * sv.z),
                                __expf(sv.w), __expf(0.2f * sv.w));
        *(float4*)&dtab[(hh * 2048 + j4) * 2]     = o0;
        *(float4*)&dtab[(hh * 2048 + j4) * 2 + 4] = o1;
    }

    const int irow = i0 + l15;             // lane's A-row (m = l15)
    const float ss = ssrc[(size_t)h * BN + (size_t)b * Nn + irow];
    const float c1 = __expf(ss), c2 = __expf(0.2f * ss);
    const unsigned char* ajr = (const unsigned char*)bitadj +
        ((size_t)b * Nn + irow) * 256 + jh * 128;
    const unsigned short* hb0 = hbf +
        ((size_t)b * 64 * 256 + (size_t)(h * HDd + l15)) * 32 + l4 * 8;
    const float* dtb = dtab + (h * 2048 + jh * 1024 + l4 * 8) * 2;

    const v8s ones = {0x3F80, 0x3F80, 0x3F80, 0x3F80, 0x3F80, 0x3F80, 0x3F80, 0x3F80};

    v4f acc0 = (v4f){0.f, 0.f, 0.f, 0.f}, acc1 = acc0, acc2 = acc0, acc3 = acc0, zac = acc0;
    v8s bbA[8], bbB[8];
    unsigned mA0, mB0, mA1, mB1;

    __syncthreads();   // dtab ready

#define LOADB(S_, BB) do {                                                    \
        const unsigned short* hq_ = hb0 +                                     \
            (size_t)((jh * 16 + ((S_) & 15)) * 16384);                        \
        BB[0] = *(const v8s*)(hq_ + 0);                                       \
        BB[1] = *(const v8s*)(hq_ + 8192);                                    \
        BB[2] = *(const v8s*)(hq_ + 512);                                     \
        BB[3] = *(const v8s*)(hq_ + 8192 + 512);                              \
        BB[4] = *(const v8s*)(hq_ + 1024);                                    \
        BB[5] = *(const v8s*)(hq_ + 8192 + 1024);                             \
        BB[6] = *(const v8s*)(hq_ + 1536);                                    \
        BB[7] = *(const v8s*)(hq_ + 8192 + 1536);                             \
    } while (0)

    // lane's two mask bytes for step S: bits j=l4*8..+7 of each 32-j group
#define LOADADJ(S_, MA_, MB_) do {                                            \
        MA_ = ajr[((S_) & 15) * 8 + l4];                                      \
        MB_ = ajr[((S_) & 15) * 8 + 4 + l4];                                  \
    } while (0)

    // w = bit ? max(c1*d1, c2*d2) : 0  ==  bit ? exp(max(s,0.2s)) : 0
#define GENFRAG(dst, M_, dd_) do {                                            \
        const float4 q0_ = *(const float4*)((dd_) + 0);                       \
        const float4 q1_ = *(const float4*)((dd_) + 4);                       \
        const float4 q2_ = *(const float4*)((dd_) + 8);                       \
        const float4 q3_ = *(const float4*)((dd_) + 12);                      \
        float w0_ = ((M_) & 1u)   ? fmaxf(c1 * q0_.x, c2 * q0_.y) : 0.f;      \
        float w1_ = ((M_) & 2u)   ? fmaxf(c1 * q0_.z, c2 * q0_.w) : 0.f;      \
        float w2_ = ((M_) & 4u)   ? fmaxf(c1 * q1_.x, c2 * q1_.y) : 0.f;      \
        float w3_ = ((M_) & 8u)   ? fmaxf(c1 * q1_.z, c2 * q1_.w) : 0.f;      \
        float w4_ = ((M_) & 16u)  ? fmaxf(c1 * q2_.x, c2 * q2_.y) : 0.f;      \
        float w5_ = ((M_) & 32u)  ? fmaxf(c1 * q2_.z, c2 * q2_.w) : 0.f;      \
        float w6_ = ((M_) & 64u)  ? fmaxf(c1 * q3_.x, c2 * q3_.y) : 0.f;      \
        float w7_ = ((M_) & 128u) ? fmaxf(c1 * q3_.z, c2 * q3_.w) : 0.f;      \
        union { v8s v; unsigned u[4]; } P_;                                   \
        asm("v_cvt_pk_bf16_f32 %0, %1, %2" : "=v"(P_.u[0]) : "v"(w0_), "v"(w1_)); \
        asm("v_cvt_pk_bf16_f32 %0, %1, %2" : "=v"(P_.u[1]) : "v"(w2_), "v"(w3_)); \
        asm("v_cvt_pk_bf16_f32 %0, %1, %2" : "=v"(P_.u[2]) : "v"(w4_), "v"(w5_)); \
        asm("v_cvt_pk_bf16_f32 %0, %1, %2" : "=v"(P_.u[3]) : "v"(w6_), "v"(w7_)); \
        dst = P_.v;                                                           \
    } while (0)

#define STEPX(S_, BB, MA_, MB_) do {                                          \
        const float* dd_ = dtb + (S_) * 128;                                  \
        v8s afr0_, afr1_;                                                     \
        GENFRAG(afr0_, MA_, dd_);                                             \
        GENFRAG(afr1_, MB_, dd_ + 64);                                        \
        acc0 = __builtin_amdgcn_mfma_f32_16x16x32_bf16(afr0_, BB[0], acc0, 0, 0, 0); \
        acc1 = __builtin_amdgcn_mfma_f32_16x16x32_bf16(afr0_, BB[2], acc1, 0, 0, 0); \
        acc2 = __builtin_amdgcn_mfma_f32_16x16x32_bf16(afr0_, BB[4], acc2, 0, 0, 0); \
        acc3 = __builtin_amdgcn_mfma_f32_16x16x32_bf16(afr0_, BB[6], acc3, 0, 0, 0); \
        zac  = __builtin_amdgcn_mfma_f32_16x16x32_bf16(afr0_, ones,  zac,  0, 0, 0); \
        acc0 = __builtin_amdgcn_mfma_f32_16x16x32_bf16(afr1_, BB[1], acc0, 0, 0, 0); \
        acc1 = __builtin_amdgcn_mfma_f32_16x16x32_bf16(afr1_, BB[3], acc1, 0, 0, 0); \
        acc2 = __builtin_amdgcn_mfma_f32_16x16x32_bf16(afr1_, BB[5], acc2, 0, 0, 0); \
        acc3 = __builtin_amdgcn_mfma_f32_16x16x32_bf16(afr1_, BB[7], acc3, 0, 0, 0); \
        zac  = __builtin_amdgcn_mfma_f32_16x16x32_bf16(afr1_, ones,  zac,  0, 0, 0); \
    } while (0)

    LOADB(0, bbA);
    LOADADJ(0, mA0, mB0);
#pragma unroll 1
    for (int s = 0; s < 16; s += 2) {
        LOADB(s + 1, bbB);                // one full step ahead of use
        LOADADJ(s + 1, mA1, mB1);
        __builtin_amdgcn_sched_barrier(0);
        STEPX(s, bbA, mA0, mB0);
        LOADB(s + 2, bbA);                // wraps harmlessly at s=14
        LOADADJ(s + 2, mA0, mB0);
        __builtin_amdgcn_sched_barrier(0);
        STEPX(s + 1, bbB, mA1, mB1);
    }

#undef LOADB
#undef LOADADJ
#undef GENFRAG
#undef STEPX

    // ---- combine j-halves via LDS (reusing dead dtab), normalize, store ----
    __syncthreads();                       // all dtab reads complete
    float* red = dtab;                     // 20 KB reuse
    float* rp = red + (h * 64 + ln) * 20;
    if (jh) {
        *(v4f*)(rp + 0)  = acc0;
        *(v4f*)(rp + 4)  = acc1;
        *(v4f*)(rp + 8)  = acc2;
        *(v4f*)(rp + 12) = acc3;
        *(v4f*)(rp + 16) = zac;
    }
    __syncthreads();
    if (!jh) {
        acc0 += *(const v4f*)(rp + 0);
        acc1 += *(const v4f*)(rp + 4);
        acc2 += *(const v4f*)(rp + 8);
        acc3 += *(const v4f*)(rp + 12);
        zac  += *(const v4f*)(rp + 16);
        float zi[4];
#pragma unroll
        for (int r = 0; r < 4; ++r) zi[r] = 1.f / zac[r];
        float* op = out + ((size_t)b * Nn + i0 + l4 * 4) * Dd + h * HDd + l15;
#pragma unroll
        for (int r = 0; r < 4; ++r) {
            op[(size_t)r * Dd + 0]  = acc0[r] * zi[r];
            op[(size_t)r * Dd + 16] = acc1[r] * zi[r];
            op[(size_t)r * Dd + 32] = acc2[r] * zi[r];
            op[(size_t)r * Dd + 48] = acc3[r] * zi[r];
        }
    }
}

extern "C" void kernel_launch(void* const* d_in, const int* in_sizes, int n_in,
                              void* d_out, int out_size, void* d_ws, size_t ws_size,
                              hipStream_t stream) {
    const float* x     = (const float*)d_in[0];
    const float* adj   = (const float*)d_in[1];
    const float* W     = (const float*)d_in[2];
    const float* a_src = (const float*)d_in[3];
    const float* a_dst = (const float*)d_in[4];
    float* out = (float*)d_out;

    // ws: hbf 4MB | ssrc [h][bn] 128KB | sdst [h][bn] 128KB | bitadj 2MB
    unsigned short* hbf = (unsigned short*)d_ws;
    float* ssrc = (float*)(hbf + (size_t)Bb * Nn * Dd);
    float* sdst = ssrc + (size_t)Hh * BN;
    unsigned long long* bitadj = (unsigned long long*)(sdst + (size_t)Hh * BN);

    k_gemm<<<dim3(1024), dim3(256), 0, stream>>>(x, W, a_src, a_dst, adj,
                                                 hbf, ssrc, sdst, bitadj);
    k_aggr<<<dim3(512), dim3(512), 0, stream>>>(hbf, bitadj, ssrc, sdst, out);
}